// Round 7
// baseline (152.194 us; speedup 1.0000x reference)
//
#include <hip/hip_runtime.h>
#include <hip/hip_fp16.h>

// EdgePredictor: score = sigmoid(dot(h[src], h[dst])) for 2M edges.
// R7: 1 memset + 2 kernels; pre_kernel INTERLEAVES convert/scatter roles
// (scatter = every 8th block) so the streaming convert (~15us) and the
// atomic scatter (~12us) overlap instead of serializing (R6: serial ~33us).
// Main kernel unchanged from R6: it sits within ~4% of the measured
// ~3.6TB/s random-128B-line fabric wall (302MB vs ~290MB byte floor).

#define N_NODES 100000
#define D_FEAT  128
#define N_EDGES 1000000
#define NTOT    (2 * N_EDGES)
#define NB      32
#define BLOCK_ROWS ((N_NODES + NB - 1) / NB)   // 3125
#define CAP     65536                           // slots/bucket (pow2)
#define NSLOTS  (NB * CAP)                      // 2,097,152

#define CURSOR_OFF 256                          // int[32]
#define H16_OFF    4096
#define H16_BYTES  ((size_t)N_NODES * D_FEAT * 2)      // 25,600,000
#define PACKED_OFF (H16_OFF + H16_BYTES)                // 16B-aligned
#define PACKED_BYTES ((size_t)NSLOTS * 8)               // 16.8 MB
#define WS_NEED    (PACKED_OFF + PACKED_BYTES)          // ~42.4 MB

#define CONV_BLOCKS (N_NODES * D_FEAT / 8 / 256)        // 6250
#define SORT_GRID   ((NTOT + 2047) / 2048)              // 977
#define PRE_GRID    (SORT_GRID * 8)                     // 7816

typedef float f4v __attribute__((ext_vector_type(4)));

__device__ __forceinline__ int detect64(const void* ea) {
    const long long* p = (const long long*)ea;
    int is64 = 1;
    #pragma unroll
    for (int i = 0; i < 8; ++i) {
        long long v = p[i];
        if (v < 0 || v >= N_NODES) is64 = 0;
    }
    return is64;
}

__device__ __forceinline__ void load_edge(const void* ea, const void* eb,
                                          int is64, long long e,
                                          int& s, int& d) {
    if (e < N_EDGES) {
        if (is64) {
            s = (int)((const long long*)ea)[e];
            d = (int)((const long long*)ea)[e + N_EDGES];
        } else {
            s = ((const int*)ea)[e];
            d = ((const int*)ea)[e + N_EDGES];
        }
    } else {
        long long e2 = e - N_EDGES;
        if (is64) {
            s = (int)((const long long*)eb)[e2];
            d = (int)((const long long*)eb)[e2 + N_EDGES];
        } else {
            s = ((const int*)eb)[e2];
            d = ((const int*)eb)[e2 + N_EDGES];
        }
    }
}

// ---- K1: interleaved convert || scatter (scatter = bid%8==0) ----
__global__ __launch_bounds__(256) void pre_kernel(
    const float* __restrict__ h, __half* __restrict__ hh,
    const void* __restrict__ ea, const void* __restrict__ eb,
    int* __restrict__ cursor, unsigned long long* __restrict__ packed) {
    int bid = blockIdx.x;
    int tid = threadIdx.x;
    if (bid & 7) {
        // convert role: 8 fp32 -> 8 fp16 per thread
        int cidx = (bid >> 3) * 7 + (bid & 7) - 1;
        if (cidx >= CONV_BLOCKS) return;
        int i = cidx * 256 + tid;
        const float4* src = (const float4*)h;
        float4 a = src[2 * i];
        float4 b = src[2 * i + 1];
        __half2 r[4];
        r[0] = __float22half2_rn(make_float2(a.x, a.y));
        r[1] = __float22half2_rn(make_float2(a.z, a.w));
        r[2] = __float22half2_rn(make_float2(b.x, b.y));
        r[3] = __float22half2_rn(make_float2(b.z, b.w));
        ((float4*)hh)[i] = *(const float4*)r;
        return;
    }
    // scatter role
    __shared__ int lh[NB];
    __shared__ int lcur[NB];
    if (tid < NB) lh[tid] = 0;
    __syncthreads();
    const int is64 = detect64(ea);
    long long base = (long long)(bid >> 3) * 2048;
    int ss[8], dd[8], ee[8];
    int cnt = 0;
    #pragma unroll
    for (int i = 0; i < 8; ++i) {
        long long e = base + i * 256 + tid;
        if (e >= NTOT) break;
        int s, d;
        load_edge(ea, eb, is64, e, s, d);
        ss[cnt] = s; dd[cnt] = d; ee[cnt] = (int)e; ++cnt;
        atomicAdd(&lh[s / BLOCK_ROWS], 1);
    }
    __syncthreads();
    if (tid < NB)
        lcur[tid] = tid * CAP + atomicAdd(&cursor[tid], lh[tid]);
    __syncthreads();
    for (int i = 0; i < cnt; ++i) {
        int b = ss[i] / BLOCK_ROWS;
        int pos = atomicAdd(&lcur[b], 1);
        packed[pos] = (unsigned long long)ss[i]
                    | ((unsigned long long)dd[i] << 17)
                    | ((unsigned long long)ee[i] << 34);
    }
}

// ---- K2: main gather, 8 lanes/edge, 2 edges/group ----
#define MAIN_GRID (NSLOTS / 64)                // 32768 blocks
#define GRID_PER_XCD (MAIN_GRID / 8)           // 4096

__device__ __forceinline__ float dot8_f16(f4v sv, f4v dv, float acc) {
    const __half2* s2 = (const __half2*)&sv;
    const __half2* d2 = (const __half2*)&dv;
#if __has_builtin(__builtin_amdgcn_fdot2)
    #pragma unroll
    for (int j = 0; j < 4; ++j)
        acc = __builtin_amdgcn_fdot2(s2[j], d2[j], acc, false);
#else
    #pragma unroll
    for (int j = 0; j < 4; ++j) {
        float2 sf = __half22float2(s2[j]);
        float2 df = __half22float2(d2[j]);
        acc += sf.x * df.x + sf.y * df.y;
    }
#endif
    return acc;
}

__global__ __launch_bounds__(256) void edge_main_sorted(
    const __half* __restrict__ hh,
    const unsigned long long* __restrict__ packed,
    const int* __restrict__ cnt,
    float* __restrict__ out) {
    // round-robin inverse: each XCD gets a contiguous 1/8 of slots
    int bid = blockIdx.x;
    int swz = (bid & 7) * GRID_PER_XCD + (bid >> 3);
    int gid = swz * 256 + threadIdx.x;
    int grp  = gid >> 3;
    int lane = gid & 7;
    int slot0 = grp << 1;                 // even; pair never straddles buckets
    int b = slot0 >> 16;                  // CAP = 2^16
    int cb = cnt[b];
    int l0 = slot0 & (CAP - 1);
    if (l0 >= cb) return;                 // tail holes (group-uniform exit)
    bool v1 = (l0 + 1) < cb;

    ulonglong2 pp = *(const ulonglong2*)(packed + slot0);
    unsigned long long p0 = pp.x;
    unsigned long long p1 = v1 ? pp.y : pp.x;   // dup edge0 if hole (no store)
    int s0 = (int)(p0 & 0x1FFFF), d0 = (int)((p0 >> 17) & 0x1FFFF), e0 = (int)(p0 >> 34);
    int s1 = (int)(p1 & 0x1FFFF), d1 = (int)((p1 >> 17) & 0x1FFFF), e1 = (int)(p1 >> 34);

    const f4v* ps0 = (const f4v*)(hh + (size_t)s0 * D_FEAT) + lane * 2;
    const f4v* pd0 = (const f4v*)(hh + (size_t)d0 * D_FEAT) + lane * 2;
    const f4v* ps1 = (const f4v*)(hh + (size_t)s1 * D_FEAT) + lane * 2;
    const f4v* pd1 = (const f4v*)(hh + (size_t)d1 * D_FEAT) + lane * 2;
    f4v sa0 = ps0[0], sb0 = ps0[1];
    f4v da0 = pd0[0], db0 = pd0[1];
    f4v sa1 = ps1[0], sb1 = ps1[1];
    f4v da1 = pd1[0], db1 = pd1[1];

    float acc0 = dot8_f16(sb0, db0, dot8_f16(sa0, da0, 0.0f));
    float acc1 = dot8_f16(sb1, db1, dot8_f16(sa1, da1, 0.0f));
    acc0 += __shfl_xor(acc0, 4, 64);
    acc0 += __shfl_xor(acc0, 2, 64);
    acc0 += __shfl_xor(acc0, 1, 64);
    acc1 += __shfl_xor(acc1, 4, 64);
    acc1 += __shfl_xor(acc1, 2, 64);
    acc1 += __shfl_xor(acc1, 1, 64);

    if (lane == 0) {
        out[e0] = 1.0f / (1.0f + expf(-acc0));
        if (v1) out[e1] = 1.0f / (1.0f + expf(-acc1));
    }
}

// ---- fallback (ws fits h16 only): unsorted fp16 ----
__global__ __launch_bounds__(256) void convert_h_fp16(
    const float* __restrict__ h, __half* __restrict__ hh) {
    int i = blockIdx.x * 256 + threadIdx.x;
    if (i >= N_NODES * D_FEAT / 8) return;
    const float4* src = (const float4*)h;
    float4 a = src[2 * i];
    float4 b = src[2 * i + 1];
    __half2 r[4];
    r[0] = __float22half2_rn(make_float2(a.x, a.y));
    r[1] = __float22half2_rn(make_float2(a.z, a.w));
    r[2] = __float22half2_rn(make_float2(b.x, b.y));
    r[3] = __float22half2_rn(make_float2(b.z, b.w));
    ((float4*)hh)[i] = *(const float4*)r;
}

__global__ __launch_bounds__(256) void edge_pred_fp16(
    const __half* __restrict__ hh,
    const void* __restrict__ ea, const void* __restrict__ eb,
    float* __restrict__ out) {
    int gid  = blockIdx.x * 256 + threadIdx.x;
    int edge = gid >> 3;
    int lane = gid & 7;
    if (edge >= NTOT) return;
    const int is64 = detect64(ea);
    int s, d;
    load_edge(ea, eb, is64, (long long)edge, s, d);
    const f4v* ps = (const f4v*)(hh + (size_t)s * D_FEAT) + lane * 2;
    const f4v* pd = (const f4v*)(hh + (size_t)d * D_FEAT) + lane * 2;
    f4v s0 = ps[0], s1 = ps[1], d0 = pd[0], d1 = pd[1];
    float acc = dot8_f16(s1, d1, dot8_f16(s0, d0, 0.0f));
    acc += __shfl_xor(acc, 4, 64);
    acc += __shfl_xor(acc, 2, 64);
    acc += __shfl_xor(acc, 1, 64);
    if (lane == 0)
        out[edge] = 1.0f / (1.0f + expf(-acc));
}

// ---- fallback (no ws): fp32 ----
__global__ __launch_bounds__(256) void edge_pred_fp32(
    const float* __restrict__ h,
    const void* __restrict__ ea, const void* __restrict__ eb,
    float* __restrict__ out) {
    int gid  = blockIdx.x * 256 + threadIdx.x;
    int edge = gid >> 4;
    int lane = gid & 15;
    if (edge >= NTOT) return;
    const int is64 = detect64(ea);
    int s, d;
    load_edge(ea, eb, is64, (long long)edge, s, d);
    const float4* ps = (const float4*)(h + (size_t)s * D_FEAT) + lane * 2;
    const float4* pd = (const float4*)(h + (size_t)d * D_FEAT) + lane * 2;
    float4 s0 = ps[0], s1 = ps[1], d0 = pd[0], d1 = pd[1];
    float acc = s0.x * d0.x + s0.y * d0.y + s0.z * d0.z + s0.w * d0.w
              + s1.x * d1.x + s1.y * d1.y + s1.z * d1.z + s1.w * d1.w;
    #pragma unroll
    for (int off = 8; off >= 1; off >>= 1)
        acc += __shfl_xor(acc, off, 64);
    if (lane == 0)
        out[edge] = 1.0f / (1.0f + expf(-acc));
}

extern "C" void kernel_launch(void* const* d_in, const int* in_sizes, int n_in,
                              void* d_out, int out_size, void* d_ws, size_t ws_size,
                              hipStream_t stream) {
    const float* h  = (const float*)d_in[0];
    const void*  ea = d_in[1];
    const void*  eb = d_in[2];
    float* out = (float*)d_out;
    char* ws = (char*)d_ws;

    const int block = 256;

    if (ws_size >= WS_NEED) {
        __half* hh  = (__half*)(ws + H16_OFF);
        int* cursor = (int*)(ws + CURSOR_OFF);
        unsigned long long* packed = (unsigned long long*)(ws + PACKED_OFF);

        hipMemsetAsync(cursor, 0, NB * sizeof(int), stream);
        pre_kernel<<<PRE_GRID, block, 0, stream>>>(h, hh, ea, eb, cursor, packed);
        edge_main_sorted<<<MAIN_GRID, block, 0, stream>>>(hh, packed, cursor, out);
    } else if (ws_size >= H16_OFF + H16_BYTES) {
        __half* hh = (__half*)(ws + H16_OFF);
        convert_h_fp16<<<CONV_BLOCKS, block, 0, stream>>>(h, hh);
        const long long tt = (long long)NTOT * 8;
        edge_pred_fp16<<<(int)((tt + block - 1) / block), block, 0, stream>>>(hh, ea, eb, out);
    } else {
        const long long tt = (long long)NTOT * 16;
        edge_pred_fp32<<<(int)((tt + block - 1) / block), block, 0, stream>>>(h, ea, eb, out);
    }
}

// Round 8
// 127.131 us; speedup vs baseline: 1.1971x; 1.1971x over previous
//
#include <hip/hip_runtime.h>
#include <hip/hip_fp16.h>

// EdgePredictor: score = sigmoid(dot(h[src], h[dst])) for 2M edges.
// R8: 1 memset + 2 kernels. pre_kernel interleaves convert/scatter with
// XCD-AWARE role assignment: per 64-block group, bids 0..7 (one per XCD
// under round-robin bid%8->XCD) run scatter; the other 56 run convert.
// (R7 used bid%8==0 -> all scatter on XCD0 -> 64us pre. R6 serial: 39us.)
// Main kernel unchanged: within ~4% of the ~3.6TB/s random-128B-line
// fabric wall (302MB observed vs ~290MB byte floor).

#define N_NODES 100000
#define D_FEAT  128
#define N_EDGES 1000000
#define NTOT    (2 * N_EDGES)
#define NB      32
#define BLOCK_ROWS ((N_NODES + NB - 1) / NB)   // 3125
#define CAP     65536                           // slots/bucket (pow2)
#define NSLOTS  (NB * CAP)                      // 2,097,152

#define CURSOR_OFF 256                          // int[32]
#define H16_OFF    4096
#define H16_BYTES  ((size_t)N_NODES * D_FEAT * 2)      // 25,600,000
#define PACKED_OFF (H16_OFF + H16_BYTES)                // 16B-aligned
#define PACKED_BYTES ((size_t)NSLOTS * 8)               // 16.8 MB
#define WS_NEED    (PACKED_OFF + PACKED_BYTES)          // ~42.4 MB

#define CONV_BLOCKS (N_NODES * D_FEAT / 8 / 256)        // 6250
#define SORT_GRID   ((NTOT + 2047) / 2048)              // 977
#define PRE_GROUPS  123                                 // ceil(977/8); 123*56=6888>=6250
#define PRE_GRID    (PRE_GROUPS * 64)                   // 7872

typedef float f4v __attribute__((ext_vector_type(4)));

__device__ __forceinline__ int detect64(const void* ea) {
    const long long* p = (const long long*)ea;
    int is64 = 1;
    #pragma unroll
    for (int i = 0; i < 8; ++i) {
        long long v = p[i];
        if (v < 0 || v >= N_NODES) is64 = 0;
    }
    return is64;
}

__device__ __forceinline__ void load_edge(const void* ea, const void* eb,
                                          int is64, long long e,
                                          int& s, int& d) {
    if (e < N_EDGES) {
        if (is64) {
            s = (int)((const long long*)ea)[e];
            d = (int)((const long long*)ea)[e + N_EDGES];
        } else {
            s = ((const int*)ea)[e];
            d = ((const int*)ea)[e + N_EDGES];
        }
    } else {
        long long e2 = e - N_EDGES;
        if (is64) {
            s = (int)((const long long*)eb)[e2];
            d = (int)((const long long*)eb)[e2 + N_EDGES];
        } else {
            s = ((const int*)eb)[e2];
            d = ((const int*)eb)[e2 + N_EDGES];
        }
    }
}

// ---- K1: interleaved convert || scatter, XCD-spread roles ----
__global__ __launch_bounds__(256) void pre_kernel(
    const float* __restrict__ h, __half* __restrict__ hh,
    const void* __restrict__ ea, const void* __restrict__ eb,
    int* __restrict__ cursor, unsigned long long* __restrict__ packed) {
    int bid = blockIdx.x;
    int tid = threadIdx.x;
    int grp = bid >> 6;
    int sub = bid & 63;
    if (sub >= 8) {
        // convert role: 8 fp32 -> 8 fp16 per thread
        int cidx = grp * 56 + sub - 8;
        if (cidx >= CONV_BLOCKS) return;
        int i = cidx * 256 + tid;
        const float4* src = (const float4*)h;
        float4 a = src[2 * i];
        float4 b = src[2 * i + 1];
        __half2 r[4];
        r[0] = __float22half2_rn(make_float2(a.x, a.y));
        r[1] = __float22half2_rn(make_float2(a.z, a.w));
        r[2] = __float22half2_rn(make_float2(b.x, b.y));
        r[3] = __float22half2_rn(make_float2(b.z, b.w));
        ((float4*)hh)[i] = *(const float4*)r;
        return;
    }
    // scatter role: one block per XCD per group
    int sidx = grp * 8 + sub;
    if (sidx >= SORT_GRID) return;
    __shared__ int lh[NB];
    __shared__ int lcur[NB];
    if (tid < NB) lh[tid] = 0;
    __syncthreads();
    const int is64 = detect64(ea);
    long long base = (long long)sidx * 2048;
    int ss[8], dd[8], ee[8];
    int cnt = 0;
    #pragma unroll
    for (int i = 0; i < 8; ++i) {
        long long e = base + i * 256 + tid;
        if (e >= NTOT) break;
        int s, d;
        load_edge(ea, eb, is64, e, s, d);
        ss[cnt] = s; dd[cnt] = d; ee[cnt] = (int)e; ++cnt;
        atomicAdd(&lh[s / BLOCK_ROWS], 1);
    }
    __syncthreads();
    if (tid < NB)
        lcur[tid] = tid * CAP + atomicAdd(&cursor[tid], lh[tid]);
    __syncthreads();
    for (int i = 0; i < cnt; ++i) {
        int b = ss[i] / BLOCK_ROWS;
        int pos = atomicAdd(&lcur[b], 1);
        packed[pos] = (unsigned long long)ss[i]
                    | ((unsigned long long)dd[i] << 17)
                    | ((unsigned long long)ee[i] << 34);
    }
}

// ---- K2: main gather, 8 lanes/edge, 2 edges/group ----
#define MAIN_GRID (NSLOTS / 64)                // 32768 blocks
#define GRID_PER_XCD (MAIN_GRID / 8)           // 4096

__device__ __forceinline__ float dot8_f16(f4v sv, f4v dv, float acc) {
    const __half2* s2 = (const __half2*)&sv;
    const __half2* d2 = (const __half2*)&dv;
#if __has_builtin(__builtin_amdgcn_fdot2)
    #pragma unroll
    for (int j = 0; j < 4; ++j)
        acc = __builtin_amdgcn_fdot2(s2[j], d2[j], acc, false);
#else
    #pragma unroll
    for (int j = 0; j < 4; ++j) {
        float2 sf = __half22float2(s2[j]);
        float2 df = __half22float2(d2[j]);
        acc += sf.x * df.x + sf.y * df.y;
    }
#endif
    return acc;
}

__global__ __launch_bounds__(256) void edge_main_sorted(
    const __half* __restrict__ hh,
    const unsigned long long* __restrict__ packed,
    const int* __restrict__ cnt,
    float* __restrict__ out) {
    // round-robin inverse: each XCD gets a contiguous 1/8 of slots
    int bid = blockIdx.x;
    int swz = (bid & 7) * GRID_PER_XCD + (bid >> 3);
    int gid = swz * 256 + threadIdx.x;
    int grp  = gid >> 3;
    int lane = gid & 7;
    int slot0 = grp << 1;                 // even; pair never straddles buckets
    int b = slot0 >> 16;                  // CAP = 2^16
    int cb = cnt[b];
    int l0 = slot0 & (CAP - 1);
    if (l0 >= cb) return;                 // tail holes (group-uniform exit)
    bool v1 = (l0 + 1) < cb;

    ulonglong2 pp = *(const ulonglong2*)(packed + slot0);
    unsigned long long p0 = pp.x;
    unsigned long long p1 = v1 ? pp.y : pp.x;   // dup edge0 if hole (no store)
    int s0 = (int)(p0 & 0x1FFFF), d0 = (int)((p0 >> 17) & 0x1FFFF), e0 = (int)(p0 >> 34);
    int s1 = (int)(p1 & 0x1FFFF), d1 = (int)((p1 >> 17) & 0x1FFFF), e1 = (int)(p1 >> 34);

    const f4v* ps0 = (const f4v*)(hh + (size_t)s0 * D_FEAT) + lane * 2;
    const f4v* pd0 = (const f4v*)(hh + (size_t)d0 * D_FEAT) + lane * 2;
    const f4v* ps1 = (const f4v*)(hh + (size_t)s1 * D_FEAT) + lane * 2;
    const f4v* pd1 = (const f4v*)(hh + (size_t)d1 * D_FEAT) + lane * 2;
    f4v sa0 = ps0[0], sb0 = ps0[1];
    f4v da0 = pd0[0], db0 = pd0[1];
    f4v sa1 = ps1[0], sb1 = ps1[1];
    f4v da1 = pd1[0], db1 = pd1[1];

    float acc0 = dot8_f16(sb0, db0, dot8_f16(sa0, da0, 0.0f));
    float acc1 = dot8_f16(sb1, db1, dot8_f16(sa1, da1, 0.0f));
    acc0 += __shfl_xor(acc0, 4, 64);
    acc0 += __shfl_xor(acc0, 2, 64);
    acc0 += __shfl_xor(acc0, 1, 64);
    acc1 += __shfl_xor(acc1, 4, 64);
    acc1 += __shfl_xor(acc1, 2, 64);
    acc1 += __shfl_xor(acc1, 1, 64);

    if (lane == 0) {
        out[e0] = 1.0f / (1.0f + expf(-acc0));
        if (v1) out[e1] = 1.0f / (1.0f + expf(-acc1));
    }
}

// ---- fallback (ws fits h16 only): unsorted fp16 ----
__global__ __launch_bounds__(256) void convert_h_fp16(
    const float* __restrict__ h, __half* __restrict__ hh) {
    int i = blockIdx.x * 256 + threadIdx.x;
    if (i >= N_NODES * D_FEAT / 8) return;
    const float4* src = (const float4*)h;
    float4 a = src[2 * i];
    float4 b = src[2 * i + 1];
    __half2 r[4];
    r[0] = __float22half2_rn(make_float2(a.x, a.y));
    r[1] = __float22half2_rn(make_float2(a.z, a.w));
    r[2] = __float22half2_rn(make_float2(b.x, b.y));
    r[3] = __float22half2_rn(make_float2(b.z, b.w));
    ((float4*)hh)[i] = *(const float4*)r;
}

__global__ __launch_bounds__(256) void edge_pred_fp16(
    const __half* __restrict__ hh,
    const void* __restrict__ ea, const void* __restrict__ eb,
    float* __restrict__ out) {
    int gid  = blockIdx.x * 256 + threadIdx.x;
    int edge = gid >> 3;
    int lane = gid & 7;
    if (edge >= NTOT) return;
    const int is64 = detect64(ea);
    int s, d;
    load_edge(ea, eb, is64, (long long)edge, s, d);
    const f4v* ps = (const f4v*)(hh + (size_t)s * D_FEAT) + lane * 2;
    const f4v* pd = (const f4v*)(hh + (size_t)d * D_FEAT) + lane * 2;
    f4v s0 = ps[0], s1 = ps[1], d0 = pd[0], d1 = pd[1];
    float acc = dot8_f16(s1, d1, dot8_f16(s0, d0, 0.0f));
    acc += __shfl_xor(acc, 4, 64);
    acc += __shfl_xor(acc, 2, 64);
    acc += __shfl_xor(acc, 1, 64);
    if (lane == 0)
        out[edge] = 1.0f / (1.0f + expf(-acc));
}

// ---- fallback (no ws): fp32 ----
__global__ __launch_bounds__(256) void edge_pred_fp32(
    const float* __restrict__ h,
    const void* __restrict__ ea, const void* __restrict__ eb,
    float* __restrict__ out) {
    int gid  = blockIdx.x * 256 + threadIdx.x;
    int edge = gid >> 4;
    int lane = gid & 15;
    if (edge >= NTOT) return;
    const int is64 = detect64(ea);
    int s, d;
    load_edge(ea, eb, is64, (long long)edge, s, d);
    const float4* ps = (const float4*)(h + (size_t)s * D_FEAT) + lane * 2;
    const float4* pd = (const float4*)(h + (size_t)d * D_FEAT) + lane * 2;
    float4 s0 = ps[0], s1 = ps[1], d0 = pd[0], d1 = pd[1];
    float acc = s0.x * d0.x + s0.y * d0.y + s0.z * d0.z + s0.w * d0.w
              + s1.x * d1.x + s1.y * d1.y + s1.z * d1.z + s1.w * d1.w;
    #pragma unroll
    for (int off = 8; off >= 1; off >>= 1)
        acc += __shfl_xor(acc, off, 64);
    if (lane == 0)
        out[edge] = 1.0f / (1.0f + expf(-acc));
}

extern "C" void kernel_launch(void* const* d_in, const int* in_sizes, int n_in,
                              void* d_out, int out_size, void* d_ws, size_t ws_size,
                              hipStream_t stream) {
    const float* h  = (const float*)d_in[0];
    const void*  ea = d_in[1];
    const void*  eb = d_in[2];
    float* out = (float*)d_out;
    char* ws = (char*)d_ws;

    const int block = 256;

    if (ws_size >= WS_NEED) {
        __half* hh  = (__half*)(ws + H16_OFF);
        int* cursor = (int*)(ws + CURSOR_OFF);
        unsigned long long* packed = (unsigned long long*)(ws + PACKED_OFF);

        hipMemsetAsync(cursor, 0, NB * sizeof(int), stream);
        pre_kernel<<<PRE_GRID, block, 0, stream>>>(h, hh, ea, eb, cursor, packed);
        edge_main_sorted<<<MAIN_GRID, block, 0, stream>>>(hh, packed, cursor, out);
    } else if (ws_size >= H16_OFF + H16_BYTES) {
        __half* hh = (__half*)(ws + H16_OFF);
        convert_h_fp16<<<CONV_BLOCKS, block, 0, stream>>>(h, hh);
        const long long tt = (long long)NTOT * 8;
        edge_pred_fp16<<<(int)((tt + block - 1) / block), block, 0, stream>>>(hh, ea, eb, out);
    } else {
        const long long tt = (long long)NTOT * 16;
        edge_pred_fp32<<<(int)((tt + block - 1) / block), block, 0, stream>>>(h, ea, eb, out);
    }
}